// Round 1
// baseline (936.251 us; speedup 1.0000x reference)
//
#include <hip/hip_runtime.h>
#include <hip/hip_bf16.h>
#include <cstdint>
#include <cstddef>

#define T_TOKENS 8192
#define DM 4096
#define NE 8
#define RANK 64

// ws layout (bytes):
//   [0, 64)            int cnt[16]          (slot*8 + e)
//   [1024, +512KiB)    int lists[2][8][8192]
//   [525312, +64KiB)   float wts[8192][2]
//   [1MiB, +4MiB)      float z[8192][2][64]   (weight-folded x@A^T)
#define WS_CNT 0
#define WS_LISTS 1024
#define WS_WTS (WS_LISTS + 2 * 8 * 8192 * 4)
#define WS_Z (1 << 20)

__global__ __launch_bounds__(64) void zero_cnt_kernel(int* __restrict__ cnt) {
    if (threadIdx.x < 16) cnt[threadIdx.x] = 0;
}

// Gate: wave = 4 tokens x (2 k-halves x 8 experts). 512 blocks x 256 threads.
__global__ __launch_bounds__(256) void gate_kernel(
    const float* __restrict__ x, const float* __restrict__ gw,
    int* __restrict__ cnt, int* __restrict__ lists, float* __restrict__ wts) {
    int tid = threadIdx.x;
    int lane = tid & 63;
    int wv = tid >> 6;
    int t2 = lane >> 4;        // token in wave: 0..3
    int sg = (lane >> 3) & 1;  // k-half
    int e = lane & 7;          // expert
    int t = blockIdx.x * 16 + wv * 4 + t2;

    const float4* xp = (const float4*)(x + (size_t)t * DM + sg * 2048);
    const float4* gp = (const float4*)(gw + (size_t)e * DM + sg * 2048);
    float a0 = 0.f, a1 = 0.f, a2 = 0.f, a3 = 0.f;
#pragma unroll 8
    for (int i = 0; i < 512; ++i) {
        float4 xv = xp[i];
        float4 gv = gp[i];
        a0 = fmaf(xv.x, gv.x, a0);
        a1 = fmaf(xv.y, gv.y, a1);
        a2 = fmaf(xv.z, gv.z, a2);
        a3 = fmaf(xv.w, gv.w, a3);
    }
    float logit = (a0 + a1) + (a2 + a3);
    logit += __shfl_xor(logit, 8, 64);  // combine the two k-halves

    // gather all 8 expert logits for this token (lanes base..base+7 hold them)
    int base = lane & 48;
    float l[8];
#pragma unroll
    for (int j = 0; j < 8; ++j) l[j] = __shfl(logit, base + j, 64);

    if ((lane & 15) == 0) {
        float m = l[0];
#pragma unroll
        for (int j = 1; j < 8; ++j) m = fmaxf(m, l[j]);
        float p[8];
#pragma unroll
        for (int j = 0; j < 8; ++j) p[j] = expf(l[j] - m);
        // top-2, numpy tie semantics: strict >, lowest index wins
        int e0 = 0;
        float p0 = p[0];
#pragma unroll
        for (int j = 1; j < 8; ++j)
            if (p[j] > p0) { p0 = p[j]; e0 = j; }
        int e1 = -1;
        float p1 = -1.0f;
#pragma unroll
        for (int j = 0; j < 8; ++j)
            if (j != e0 && p[j] > p1) { p1 = p[j]; e1 = j; }
        float inv = 1.0f / (p0 + p1);
        wts[t * 2 + 0] = p0 * inv;
        wts[t * 2 + 1] = p1 * inv;
        int pos0 = atomicAdd(&cnt[e0], 1);
        lists[(0 * 8 + e0) * T_TOKENS + pos0] = t;
        int pos1 = atomicAdd(&cnt[8 + e1], 1);
        lists[(1 * 8 + e1) * T_TOKENS + pos1] = t;
    }
}

// Phase A: z[t][slot][r] = w * (x[t] . A_e[r]) for bucketed tokens.
// Tile M=64 tokens x N=64 ranks x BK=64. 4x4 register blocking per thread.
#define TILES_A 36
__global__ __launch_bounds__(256) void lora_a_kernel(
    const float* __restrict__ x, const float* __restrict__ A,
    const int* __restrict__ cnt, const int* __restrict__ lists,
    const float* __restrict__ wts, float* __restrict__ z) {
    int e = blockIdx.y;
    int slot = blockIdx.z;
    int count = cnt[slot * 8 + e];

    __shared__ float xs[64 * 64];  // [kk][m]
    __shared__ float as[64 * 64];  // [kk][r]
    __shared__ int stok[64];
    __shared__ float sw[64];

    int tid = threadIdx.x;
    const int m4 = tid & 15, n4 = tid >> 4;
    const int lt = tid >> 2, c = tid & 3;
    const int listbase = (slot * 8 + e) * T_TOKENS;

    for (int ti = blockIdx.x; ti * 64 < count; ti += TILES_A) {
        int t0 = ti * 64;
        __syncthreads();  // protect LDS reuse across ti iterations
        if (tid < 64) {
            int idx = t0 + tid;
            int tk;
            float w;
            if (idx < count) {
                tk = lists[listbase + idx];
                w = wts[tk * 2 + slot];
            } else {
                tk = lists[listbase];  // valid: t0 < count
                w = 0.0f;
            }
            stok[tid] = tk;
            sw[tid] = w;
        }
        __syncthreads();
        int xrow = stok[lt];
        const float* xbase = x + (size_t)xrow * DM + c * 16;
        const float* abase = A + ((size_t)e * RANK + lt) * DM + c * 16;

        float acc[4][4] = {};

        for (int kc = 0; kc < 64; ++kc) {
            __syncthreads();
#pragma unroll
            for (int j = 0; j < 4; ++j) {
                float4 xv = *(const float4*)(xbase + kc * 64 + j * 4);
                float4 av = *(const float4*)(abase + kc * 64 + j * 4);
                int kk = c * 16 + j * 4;
                xs[(kk + 0) * 64 + lt] = xv.x;
                xs[(kk + 1) * 64 + lt] = xv.y;
                xs[(kk + 2) * 64 + lt] = xv.z;
                xs[(kk + 3) * 64 + lt] = xv.w;
                as[(kk + 0) * 64 + lt] = av.x;
                as[(kk + 1) * 64 + lt] = av.y;
                as[(kk + 2) * 64 + lt] = av.z;
                as[(kk + 3) * 64 + lt] = av.w;
            }
            __syncthreads();
#pragma unroll 4
            for (int kk = 0; kk < 64; ++kk) {
                float4 xv = *(const float4*)&xs[kk * 64 + m4 * 4];
                float4 av = *(const float4*)&as[kk * 64 + n4 * 4];
                float ax[4] = {xv.x, xv.y, xv.z, xv.w};
                float aa[4] = {av.x, av.y, av.z, av.w};
#pragma unroll
                for (int i = 0; i < 4; ++i)
#pragma unroll
                    for (int j = 0; j < 4; ++j)
                        acc[i][j] = fmaf(ax[i], aa[j], acc[i][j]);
            }
        }
        // fold routing weight into z at write
#pragma unroll
        for (int i = 0; i < 4; ++i) {
            int m = m4 * 4 + i;
            if (t0 + m < count) {
                int tk = stok[m];
                float w = sw[m];
                float4 o = make_float4(acc[i][0] * w, acc[i][1] * w,
                                       acc[i][2] * w, acc[i][3] * w);
                *(float4*)(z + ((size_t)tk * 2 + slot) * RANK + n4 * 4) = o;
            }
        }
    }
}

// Phase B: out[t][d] (+)= z[t][slot] . B_e[d][:]. Tile M=64 tokens x N=64 d, K=64.
// slot 0 overwrites, slot 1 read-add-writes (each token appears once per slot -> no atomics).
#define TILES_B 36
__global__ __launch_bounds__(256) void lora_b_kernel(
    const float* __restrict__ z, const float* __restrict__ B,
    const int* __restrict__ cnt, const int* __restrict__ lists,
    float* __restrict__ out, int slot) {
    int e = blockIdx.z;
    int count = cnt[slot * 8 + e];
    int d0 = blockIdx.x * 64;

    __shared__ float zs[64 * 64];  // [r][m]
    __shared__ int stok[64];

    int tid = threadIdx.x;
    const int m4 = tid & 15, n4 = tid >> 4;
    const int lt = tid >> 2, c = tid & 3;
    const float* Bb = B + (size_t)e * DM * RANK;
    const int listbase = (slot * 8 + e) * T_TOKENS;

    for (int ti = blockIdx.y; ti * 64 < count; ti += TILES_B) {
        int t0 = ti * 64;
        __syncthreads();
        if (tid < 64) {
            int idx = t0 + tid;
            stok[tid] = (idx < count) ? lists[listbase + idx] : -1;
        }
        __syncthreads();
        {
            int tk = stok[lt];
            int tkc = tk < 0 ? 0 : tk;
            const float* zb = z + ((size_t)tkc * 2 + slot) * RANK + c * 16;
#pragma unroll
            for (int j = 0; j < 4; ++j) {
                float4 v = *(const float4*)(zb + j * 4);
                int r = c * 16 + j * 4;
                zs[(r + 0) * 64 + lt] = v.x;
                zs[(r + 1) * 64 + lt] = v.y;
                zs[(r + 2) * 64 + lt] = v.z;
                zs[(r + 3) * 64 + lt] = v.w;
            }
        }
        __syncthreads();

        float acc[4][4] = {};
#pragma unroll 1
        for (int rc = 0; rc < 8; ++rc) {
            float bb[4][8];
#pragma unroll
            for (int j = 0; j < 4; ++j) {
                const float* bp = Bb + (size_t)(d0 + n4 * 4 + j) * RANK + rc * 8;
                float4 v0 = *(const float4*)bp;
                float4 v1 = *(const float4*)(bp + 4);
                bb[j][0] = v0.x; bb[j][1] = v0.y; bb[j][2] = v0.z; bb[j][3] = v0.w;
                bb[j][4] = v1.x; bb[j][5] = v1.y; bb[j][6] = v1.z; bb[j][7] = v1.w;
            }
#pragma unroll
            for (int rr = 0; rr < 8; ++rr) {
                int r = rc * 8 + rr;
                float4 zv = *(const float4*)&zs[r * 64 + m4 * 4];
                float zz[4] = {zv.x, zv.y, zv.z, zv.w};
#pragma unroll
                for (int i = 0; i < 4; ++i)
#pragma unroll
                    for (int j = 0; j < 4; ++j)
                        acc[i][j] = fmaf(zz[i], bb[j][rr], acc[i][j]);
            }
        }
#pragma unroll
        for (int i = 0; i < 4; ++i) {
            int m = m4 * 4 + i;
            int tk = stok[m];
            if (tk >= 0) {
                float* op = out + (size_t)tk * DM + d0 + n4 * 4;
                float4 o = make_float4(acc[i][0], acc[i][1], acc[i][2], acc[i][3]);
                if (slot == 1) {
                    float4 prev = *(const float4*)op;
                    o.x += prev.x; o.y += prev.y; o.z += prev.z; o.w += prev.w;
                }
                *(float4*)op = o;
            }
        }
    }
}

extern "C" void kernel_launch(void* const* d_in, const int* in_sizes, int n_in,
                              void* d_out, int out_size, void* d_ws, size_t ws_size,
                              hipStream_t stream) {
    const float* x = (const float*)d_in[0];
    const float* gw = (const float*)d_in[1];
    const float* A = (const float*)d_in[2];
    const float* Bm = (const float*)d_in[3];
    float* out = (float*)d_out;
    char* ws = (char*)d_ws;
    int* cnt = (int*)(ws + WS_CNT);
    int* lists = (int*)(ws + WS_LISTS);
    float* wts = (float*)(ws + WS_WTS);
    float* z = (float*)(ws + WS_Z);

    zero_cnt_kernel<<<1, 64, 0, stream>>>(cnt);
    gate_kernel<<<512, 256, 0, stream>>>(x, gw, cnt, lists, wts);
    lora_a_kernel<<<dim3(TILES_A, 8, 2), 256, 0, stream>>>(x, A, cnt, lists, wts, z);
    lora_b_kernel<<<dim3(64, TILES_B, 8), 256, 0, stream>>>(z, Bm, cnt, lists, out, 0);
    lora_b_kernel<<<dim3(64, TILES_B, 8), 256, 0, stream>>>(z, Bm, cnt, lists, out, 1);
}

// Round 2
// 611.964 us; speedup vs baseline: 1.5299x; 1.5299x over previous
//
#include <hip/hip_runtime.h>
#include <hip/hip_bf16.h>
#include <cstdint>
#include <cstddef>

#define T_TOKENS 8192
#define DM 4096
#define NE 8
#define RANK 64

// ws layout (bytes):
//   [0, 64)        int cnt[16]              (slot*8 + e)
//   [1024, +512K)  int lists[2][8][8192]
//   [525312,+64K)  float wts[8192][2]
//   [1M, +8M)      float zpart[2][8192][2][64]   (k-split partials of x@A^T)
//   [10M, +2M)     ushort zbf[8192][2][64]        (weight-folded, bf16)
#define WS_CNT 0
#define WS_LISTS 1024
#define WS_WTS (WS_LISTS + 2 * 8 * 8192 * 4)
#define WS_ZPART (1 << 20)
#define WS_ZBF (10 << 20)
#define ZP (8192 * 2 * 64)

typedef __attribute__((ext_vector_type(8))) short bfrag;
typedef __attribute__((ext_vector_type(4))) float f4acc;

__device__ __forceinline__ unsigned short f2bf(float f) {
    unsigned int u = __float_as_uint(f);
    return (unsigned short)((u + 0x7FFF + ((u >> 16) & 1)) >> 16);
}

__global__ __launch_bounds__(64) void zero_cnt_kernel(int* __restrict__ cnt) {
    if (threadIdx.x < 16) cnt[threadIdx.x] = 0;
}

// Gate: wave = 4 tokens x (2 k-halves x 8 experts). 512 blocks x 256 threads. (fp32, verified R1)
__global__ __launch_bounds__(256) void gate_kernel(
    const float* __restrict__ x, const float* __restrict__ gw,
    int* __restrict__ cnt, int* __restrict__ lists, float* __restrict__ wts) {
    int tid = threadIdx.x;
    int lane = tid & 63;
    int wv = tid >> 6;
    int t2 = lane >> 4;
    int sg = (lane >> 3) & 1;
    int e = lane & 7;
    int t = blockIdx.x * 16 + wv * 4 + t2;

    const float4* xp = (const float4*)(x + (size_t)t * DM + sg * 2048);
    const float4* gp = (const float4*)(gw + (size_t)e * DM + sg * 2048);
    float a0 = 0.f, a1 = 0.f, a2 = 0.f, a3 = 0.f;
#pragma unroll 8
    for (int i = 0; i < 512; ++i) {
        float4 xv = xp[i];
        float4 gv = gp[i];
        a0 = fmaf(xv.x, gv.x, a0);
        a1 = fmaf(xv.y, gv.y, a1);
        a2 = fmaf(xv.z, gv.z, a2);
        a3 = fmaf(xv.w, gv.w, a3);
    }
    float logit = (a0 + a1) + (a2 + a3);
    logit += __shfl_xor(logit, 8, 64);

    int base = lane & 48;
    float l[8];
#pragma unroll
    for (int j = 0; j < 8; ++j) l[j] = __shfl(logit, base + j, 64);

    if ((lane & 15) == 0) {
        float m = l[0];
#pragma unroll
        for (int j = 1; j < 8; ++j) m = fmaxf(m, l[j]);
        float p[8];
#pragma unroll
        for (int j = 0; j < 8; ++j) p[j] = expf(l[j] - m);
        int e0 = 0;
        float p0 = p[0];
#pragma unroll
        for (int j = 1; j < 8; ++j)
            if (p[j] > p0) { p0 = p[j]; e0 = j; }
        int e1 = -1;
        float p1 = -1.0f;
#pragma unroll
        for (int j = 0; j < 8; ++j)
            if (j != e0 && p[j] > p1) { p1 = p[j]; e1 = j; }
        float inv = 1.0f / (p0 + p1);
        wts[t * 2 + 0] = p0 * inv;
        wts[t * 2 + 1] = p1 * inv;
        int pos0 = atomicAdd(&cnt[e0], 1);
        lists[(0 * 8 + e0) * T_TOKENS + pos0] = t;
        int pos1 = atomicAdd(&cnt[8 + e1], 1);
        lists[(1 * 8 + e1) * T_TOKENS + pos1] = t;
    }
}

// Phase A (MFMA): zpart[kh][t][slot][r] = x[t, kh-half] @ A_e[r, kh-half]^T
// Block: M=64 gathered tokens x N=64 ranks, K=2048 (half), BK=128. 4 waves.
#define TILES_A 20
#define BKA 128
#define PITCH_A 136  // 128 + 8 bf16 pad -> 2-way LDS read conflicts (free)
__global__ __launch_bounds__(256) void lora_a_mfma(
    const float* __restrict__ x, const float* __restrict__ A,
    const int* __restrict__ cnt, const int* __restrict__ lists,
    float* __restrict__ zpart) {
    int e = blockIdx.y;
    int sk = blockIdx.z;
    int slot = sk >> 1, kh = sk & 1;
    int count = cnt[slot * 8 + e];

    __shared__ __attribute__((aligned(16))) unsigned short xs[64 * PITCH_A];
    __shared__ __attribute__((aligned(16))) unsigned short as[64 * PITCH_A];
    __shared__ int stok[64];

    int tid = threadIdx.x;
    int wave = tid >> 6, lane = tid & 63;
    int q = lane >> 4, col = lane & 15;
    int srow = tid >> 2, sc = tid & 3;  // staging: row, 32-k chunk
    const int listbase = (slot * 8 + e) * T_TOKENS;
    float* zout = zpart + (size_t)kh * ZP;

    for (int ti = blockIdx.x; ti * 64 < count; ti += TILES_A) {
        int t0 = ti * 64;
        __syncthreads();
        if (tid < 64) {
            int idx = t0 + tid;
            stok[tid] = (idx < count) ? lists[listbase + idx] : lists[listbase];
        }
        __syncthreads();

        const float* xrow = x + (size_t)stok[srow] * DM + kh * 2048 + sc * 32;
        const float* arow = A + ((size_t)e * RANK + srow) * DM + kh * 2048 + sc * 32;

        f4acc acc[4] = {};

        for (int kb = 0; kb < 2048; kb += BKA) {
            __syncthreads();
            // stage x-tile and A-tile (fp32 -> bf16 during staging)
#pragma unroll
            for (int j = 0; j < 4; ++j) {
                float4 v0 = *(const float4*)(xrow + kb + j * 8);
                float4 v1 = *(const float4*)(xrow + kb + j * 8 + 4);
                unsigned short tmp[8] = {f2bf(v0.x), f2bf(v0.y), f2bf(v0.z), f2bf(v0.w),
                                         f2bf(v1.x), f2bf(v1.y), f2bf(v1.z), f2bf(v1.w)};
                *(bfrag*)&xs[srow * PITCH_A + sc * 32 + j * 8] = *(bfrag*)tmp;
                float4 w0 = *(const float4*)(arow + kb + j * 8);
                float4 w1 = *(const float4*)(arow + kb + j * 8 + 4);
                unsigned short tm2[8] = {f2bf(w0.x), f2bf(w0.y), f2bf(w0.z), f2bf(w0.w),
                                         f2bf(w1.x), f2bf(w1.y), f2bf(w1.z), f2bf(w1.w)};
                *(bfrag*)&as[srow * PITCH_A + sc * 32 + j * 8] = *(bfrag*)tm2;
            }
            __syncthreads();
#pragma unroll
            for (int ks = 0; ks < BKA / 32; ++ks) {
                bfrag af = *(const bfrag*)&xs[(wave * 16 + col) * PITCH_A + ks * 32 + q * 8];
#pragma unroll
                for (int nt = 0; nt < 4; ++nt) {
                    bfrag bf = *(const bfrag*)&as[(nt * 16 + col) * PITCH_A + ks * 32 + q * 8];
                    acc[nt] = __builtin_amdgcn_mfma_f32_16x16x32_bf16(af, bf, acc[nt], 0, 0, 0);
                }
            }
        }
        // D layout: row = q*4 + reg, col = lane&15
#pragma unroll
        for (int nt = 0; nt < 4; ++nt) {
#pragma unroll
            for (int r = 0; r < 4; ++r) {
                int mm = wave * 16 + q * 4 + r;
                if (t0 + mm < count) {
                    int tk = stok[mm];
                    zout[((size_t)tk * 2 + slot) * RANK + nt * 16 + col] = acc[nt][r];
                }
            }
        }
    }
}

// Reduce k-split partials, fold routing weight, emit bf16 z.
__global__ __launch_bounds__(256) void zreduce_kernel(
    const float* __restrict__ zpart, const float* __restrict__ wts,
    unsigned short* __restrict__ zbf) {
    int i = blockIdx.x * 256 + threadIdx.x;  // over 262144 float4 groups
    float4 a = ((const float4*)zpart)[i];
    float4 b = ((const float4*)(zpart + ZP))[i];
    float w = wts[i >> 4];
    ushort4 o;
    o.x = f2bf((a.x + b.x) * w);
    o.y = f2bf((a.y + b.y) * w);
    o.z = f2bf((a.z + b.z) * w);
    o.w = f2bf((a.w + b.w) * w);
    ((ushort4*)zbf)[i] = o;
}

// Phase B (MFMA): out[t][d] (+)= z_bf16[t][slot] . B_e[d][:]. M=64 tokens x N=128 d, K=64.
#define TILES_B2 16
#define PITCH_B 72  // 64 + 8 bf16 pad
__global__ __launch_bounds__(256) void lora_b_mfma(
    const unsigned short* __restrict__ zbf, const float* __restrict__ B,
    const int* __restrict__ cnt, const int* __restrict__ lists,
    float* __restrict__ out, int slot) {
    int e = blockIdx.z;
    int count = cnt[slot * 8 + e];
    int d0 = blockIdx.x * 128;

    __shared__ __attribute__((aligned(16))) unsigned short zs[64 * PITCH_B];
    __shared__ __attribute__((aligned(16))) unsigned short bs[128 * PITCH_B];
    __shared__ int stok[64];

    int tid = threadIdx.x;
    int wave = tid >> 6, lane = tid & 63;
    int q = lane >> 4, col = lane & 15;
    const int listbase = (slot * 8 + e) * T_TOKENS;

    // stage B tile once (constant across token tiles): row = tid>>1, half = tid&1
    {
        int row = tid >> 1, h = tid & 1;
        const float* bp = B + ((size_t)e * DM + d0 + row) * RANK + h * 32;
#pragma unroll
        for (int j = 0; j < 4; ++j) {
            float4 v0 = *(const float4*)(bp + j * 8);
            float4 v1 = *(const float4*)(bp + j * 8 + 4);
            unsigned short tmp[8] = {f2bf(v0.x), f2bf(v0.y), f2bf(v0.z), f2bf(v0.w),
                                     f2bf(v1.x), f2bf(v1.y), f2bf(v1.z), f2bf(v1.w)};
            *(bfrag*)&bs[row * PITCH_B + h * 32 + j * 8] = *(bfrag*)tmp;
        }
    }

    for (int ti = blockIdx.y; ti * 64 < count; ti += TILES_B2) {
        int t0 = ti * 64;
        __syncthreads();
        if (tid < 64) {
            int idx = t0 + tid;
            stok[tid] = (idx < count) ? lists[listbase + idx] : -1;
        }
        __syncthreads();
        // stage z tile: row = tid>>2, 16-bf16 chunk c = tid&3
        {
            int row = tid >> 2, c = tid & 3;
            int tk = stok[row];
            int tkc = tk < 0 ? 0 : tk;
            const uint4* zp = (const uint4*)(zbf + ((size_t)tkc * 2 + slot) * RANK + c * 16);
            uint4 v0 = zp[0];
            uint4 v1 = zp[1];
            *(uint4*)&zs[row * PITCH_B + c * 16] = v0;
            *(uint4*)&zs[row * PITCH_B + c * 16 + 8] = v1;
        }
        __syncthreads();

        f4acc acc[8] = {};
#pragma unroll
        for (int ks = 0; ks < 2; ++ks) {
            bfrag af = *(const bfrag*)&zs[(wave * 16 + col) * PITCH_B + ks * 32 + q * 8];
#pragma unroll
            for (int nt = 0; nt < 8; ++nt) {
                bfrag bf = *(const bfrag*)&bs[(nt * 16 + col) * PITCH_B + ks * 32 + q * 8];
                acc[nt] = __builtin_amdgcn_mfma_f32_16x16x32_bf16(af, bf, acc[nt], 0, 0, 0);
            }
        }
#pragma unroll
        for (int r = 0; r < 4; ++r) {
            int mm = wave * 16 + q * 4 + r;
            int tk = stok[mm];
            if (tk >= 0) {
                float* op = out + (size_t)tk * DM + d0 + col;
                if (slot == 0) {
#pragma unroll
                    for (int nt = 0; nt < 8; ++nt) op[nt * 16] = acc[nt][r];
                } else {
#pragma unroll
                    for (int nt = 0; nt < 8; ++nt) op[nt * 16] += acc[nt][r];
                }
            }
        }
    }
}

extern "C" void kernel_launch(void* const* d_in, const int* in_sizes, int n_in,
                              void* d_out, int out_size, void* d_ws, size_t ws_size,
                              hipStream_t stream) {
    const float* x = (const float*)d_in[0];
    const float* gw = (const float*)d_in[1];
    const float* A = (const float*)d_in[2];
    const float* Bm = (const float*)d_in[3];
    float* out = (float*)d_out;
    char* ws = (char*)d_ws;
    int* cnt = (int*)(ws + WS_CNT);
    int* lists = (int*)(ws + WS_LISTS);
    float* wts = (float*)(ws + WS_WTS);
    float* zpart = (float*)(ws + WS_ZPART);
    unsigned short* zbf = (unsigned short*)(ws + WS_ZBF);

    zero_cnt_kernel<<<1, 64, 0, stream>>>(cnt);
    gate_kernel<<<512, 256, 0, stream>>>(x, gw, cnt, lists, wts);
    lora_a_mfma<<<dim3(TILES_A, 8, 4), 256, 0, stream>>>(x, A, cnt, lists, zpart);
    zreduce_kernel<<<1024, 256, 0, stream>>>(zpart, wts, zbf);
    lora_b_mfma<<<dim3(32, TILES_B2, 8), 256, 0, stream>>>(zbf, Bm, cnt, lists, out, 0);
    lora_b_mfma<<<dim3(32, TILES_B2, 8), 256, 0, stream>>>(zbf, Bm, cnt, lists, out, 1);
}